// Round 7
// baseline (184.361 us; speedup 1.0000x reference)
//
#include <hip/hip_runtime.h>
#include <math.h>

#define BETA  0.125f    // 1/sqrt(64)
#define SHIFT 30.0f     // fixed softmax shift; logits bounded in [0.125, 68.5]
#define EPSF  1e-7f

typedef __attribute__((ext_vector_type(8))) short short8;
typedef __attribute__((ext_vector_type(4))) short short4v;
typedef __attribute__((ext_vector_type(4))) float f32x4;

__device__ __forceinline__ unsigned short bf16_rne(float x) {
  unsigned int u = __float_as_uint(x);
  return (unsigned short)((u + 0x7fffu + ((u >> 16) & 1u)) >> 16);
}
__device__ __forceinline__ float bf16_tof(unsigned short h) {
  return __uint_as_float(((unsigned int)h) << 16);
}
__device__ __forceinline__ void split2(float x, unsigned short& h, unsigned short& l) {
  unsigned int u = __float_as_uint(x);
  unsigned int hr = (u + 0x7fffu + ((u >> 16) & 1u)) & 0xffff0000u;  // RNE hi
  h = (unsigned short)(hr >> 16);
  l = bf16_rne(x - __uint_as_float(hr));
}

// ---------------------------------------------------------------------------
// Merged projection. Blocks 0..63: Q; 64..191: K; 192..319: V (double proj).
// Outputs: y0 = cosh (f32), spatial part split bf16 hi/lo (row-major only;
// the V transpose is a separate kernel).
// ---------------------------------------------------------------------------
__global__ __launch_bounds__(256) void proj_kernel(
    const float* __restrict__ Xq, const float* __restrict__ Xk,
    const float* __restrict__ Xv,
    const float* __restrict__ Wq, const float* __restrict__ bq,
    const float* __restrict__ Wk, const float* __restrict__ bk,
    const float* __restrict__ Wv, const float* __restrict__ bv,
    float* __restrict__ Q0, float* __restrict__ K0, float* __restrict__ V0,
    unsigned short* __restrict__ Qh, unsigned short* __restrict__ Ql,
    unsigned short* __restrict__ Kh, unsigned short* __restrict__ Kl,
    unsigned short* __restrict__ Vh, unsigned short* __restrict__ Vl)
{
  __shared__ float Xs[64 * 64];
  __shared__ float Ws[64 * 64];

  const int bid = blockIdx.x;
  const float *X, *W, *bias;
  float* y0;
  unsigned short *yh, *yl;
  bool dbl;
  int rowBase;
  if (bid < 64)       { X = Xq; W = Wq; bias = bq; y0 = Q0; yh = Qh; yl = Ql; rowBase = bid << 6;         dbl = false; }
  else if (bid < 192) { X = Xk; W = Wk; bias = bk; y0 = K0; yh = Kh; yl = Kl; rowBase = (bid - 64) << 6;  dbl = false; }
  else                { X = Xv; W = Wk; bias = bk; y0 = V0; yh = Vh; yl = Vl; rowBase = (bid - 192) << 6; dbl = true;  }

  const int tid = threadIdx.x;
  const int ty = tid >> 4, tx = tid & 15;
  const int ty4 = ty << 2, tx4 = tx << 2;

  float acc[4][4];
#pragma unroll
  for (int j = 0; j < 4; ++j) {
    float bj = bias[tx4 + j];
#pragma unroll
    for (int i = 0; i < 4; ++i) acc[i][j] = bj;
  }

  for (int kc = 0; kc < 4; ++kc) {
#pragma unroll
    for (int q = 0; q < 4; ++q) {
      int f = tid + (q << 8);
      int r = f >> 4, g = f & 15;
      int sw = (r << 6) + ((g ^ (r >> 2)) << 2);
      *(float4*)&Xs[sw] = *(const float4*)&X[(rowBase + r) * 256 + (kc << 6) + (g << 2)];
      *(float4*)&Ws[sw] = *(const float4*)&W[r * 256 + (kc << 6) + (g << 2)];
    }
    __syncthreads();
#pragma unroll 4
    for (int kk = 0; kk < 64; kk += 4) {
      const int gk = kk >> 2;
      float4 xa[4], wb[4];
#pragma unroll
      for (int i = 0; i < 4; ++i)
        xa[i] = *(const float4*)&Xs[((ty4 + i) << 6) + ((gk ^ ty) << 2)];
#pragma unroll
      for (int j = 0; j < 4; ++j)
        wb[j] = *(const float4*)&Ws[((tx4 + j) << 6) + ((gk ^ tx) << 2)];
#pragma unroll
      for (int i = 0; i < 4; ++i)
#pragma unroll
        for (int j = 0; j < 4; ++j)
          acc[i][j] += xa[i].x * wb[j].x + xa[i].y * wb[j].y +
                       xa[i].z * wb[j].z + xa[i].w * wb[j].w;
    }
    __syncthreads();
  }

  if (dbl) {
#pragma unroll
    for (int i = 0; i < 4; ++i) {
      float4 v = make_float4(acc[i][0], acc[i][1], acc[i][2], acc[i][3]);
      *(float4*)&Xs[((ty4 + i) << 6) + ((tx ^ ty) << 2)] = v;
    }
#pragma unroll
    for (int q = 0; q < 4; ++q) {
      int f = tid + (q << 8);
      int r = f >> 4, g = f & 15;
      int sw = (r << 6) + ((g ^ (r >> 2)) << 2);
      *(float4*)&Ws[sw] = *(const float4*)&Wv[(r << 6) + (g << 2)];
    }
#pragma unroll
    for (int j = 0; j < 4; ++j) {
      float bj = bv[tx4 + j];
#pragma unroll
      for (int i = 0; i < 4; ++i) acc[i][j] = bj;
    }
    __syncthreads();
#pragma unroll 4
    for (int kk = 0; kk < 64; kk += 4) {
      const int gk = kk >> 2;
      float4 xa[4], wb[4];
#pragma unroll
      for (int i = 0; i < 4; ++i)
        xa[i] = *(const float4*)&Xs[((ty4 + i) << 6) + ((gk ^ ty) << 2)];
#pragma unroll
      for (int j = 0; j < 4; ++j)
        wb[j] = *(const float4*)&Ws[((tx4 + j) << 6) + ((gk ^ tx) << 2)];
#pragma unroll
      for (int i = 0; i < 4; ++i)
#pragma unroll
        for (int j = 0; j < 4; ++j)
          acc[i][j] += xa[i].x * wb[j].x + xa[i].y * wb[j].y +
                       xa[i].z * wb[j].z + xa[i].w * wb[j].w;
    }
  }

  // expmap0 epilogue in registers + shuffles
  float n2p[4];
#pragma unroll
  for (int i = 0; i < 4; ++i)
    n2p[i] = acc[i][0] * acc[i][0] + acc[i][1] * acc[i][1] +
             acc[i][2] * acc[i][2] + acc[i][3] * acc[i][3];
#pragma unroll
  for (int i = 0; i < 4; ++i) {
    n2p[i] += __shfl_xor(n2p[i], 1);
    n2p[i] += __shfl_xor(n2p[i], 2);
    n2p[i] += __shfl_xor(n2p[i], 4);
    n2p[i] += __shfl_xor(n2p[i], 8);
  }
#pragma unroll
  for (int i = 0; i < 4; ++i) {
    float n = sqrtf(n2p[i]);
    float factor = fminf(3.5f / (n + EPSF), 1.0f);
    float xn = fmaxf(n * factor, EPSF);
    float et = __expf(xn);
    float rt = __builtin_amdgcn_rcpf(et);
    float ch = 0.5f * (et + rt);
    float sh = 0.5f * (et - rt);
    float scale = sh * factor * __builtin_amdgcn_rcpf(xn);
    int row = rowBase + ty4 + i;
    if (tx == 0) y0[row] = ch;
    unsigned short h[4], l[4];
#pragma unroll
    for (int j = 0; j < 4; ++j) split2(acc[i][j] * scale, h[j], l[j]);
    unsigned int* ph = (unsigned int*)(yh + row * 64 + tx4);
    ph[0] = (unsigned int)h[0] | ((unsigned int)h[1] << 16);
    ph[1] = (unsigned int)h[2] | ((unsigned int)h[3] << 16);
    unsigned int* pl = (unsigned int*)(yl + row * 64 + tx4);
    pl[0] = (unsigned int)l[0] | ((unsigned int)l[1] << 16);
    pl[1] = (unsigned int)l[2] | ((unsigned int)l[3] << 16);
  }
}

// ---------------------------------------------------------------------------
// Standalone transpose: Vh/Vl [8192][64] u16 -> Vth/Vtl [64][8192] u16.
// Grid 256: blockIdx.x&127 = 64-row tile, >=128 selects the lo array.
// LDS holds the tile as one u32 per u16 at row stride 65 (2-way max aliasing).
// ---------------------------------------------------------------------------
__global__ __launch_bounds__(256) void transpose_kernel(
    const unsigned short* __restrict__ Vh, const unsigned short* __restrict__ Vl,
    unsigned short* __restrict__ Vth, unsigned short* __restrict__ Vtl)
{
  __shared__ unsigned int L[64 * 65];
  const int tid = threadIdx.x;
  const int tile = blockIdx.x & 127;
  const bool isL = blockIdx.x >= 128;
  const unsigned short* src = isL ? Vl : Vh;
  unsigned short* dst = isL ? Vtl : Vth;
  const int rowBase = tile << 6;

#pragma unroll
  for (int q = 0; q < 2; ++q) {
    int f = tid + (q << 8);        // 0..511
    int r = f >> 3;                // 0..63
    int c8 = (f & 7) << 3;         // 0,8,..,56
    uint4 v = *(const uint4*)&src[(rowBase + r) * 64 + c8];
    unsigned int* Lr = &L[r * 65 + c8];
    Lr[0] = v.x & 0xffffu; Lr[1] = v.x >> 16;
    Lr[2] = v.y & 0xffffu; Lr[3] = v.y >> 16;
    Lr[4] = v.z & 0xffffu; Lr[5] = v.z >> 16;
    Lr[6] = v.w & 0xffffu; Lr[7] = v.w >> 16;
  }
  __syncthreads();
#pragma unroll
  for (int q = 0; q < 2; ++q) {
    int f = tid + (q << 8);
    int d = f >> 3;                // 0..63
    int seg = (f & 7) << 3;        // 0..56
    unsigned int o[4];
#pragma unroll
    for (int k = 0; k < 4; ++k)
      o[k] = L[(seg + 2 * k) * 65 + d] | (L[(seg + 2 * k + 1) * 65 + d] << 16);
    *(uint4*)&dst[d * 8192 + rowBase + seg] = make_uint4(o[0], o[1], o[2], o[3]);
  }
}

// ---------------------------------------------------------------------------
// MFMA attention core (round-5 body, tripwire-proven). One wave = 32 s-rows
// x one m-slice; per-wave-private LDS, zero __syncthreads.
// ---------------------------------------------------------------------------
__global__ void __attribute__((amdgpu_waves_per_eu(2, 4)))
__launch_bounds__(256) attn_kernel(
    const float* __restrict__ Q0g, const unsigned short* __restrict__ Qh,
    const unsigned short* __restrict__ Ql,
    const float* __restrict__ K0g, const unsigned short* __restrict__ Kh,
    const unsigned short* __restrict__ Kl,
    const float* __restrict__ V0g, const unsigned short* __restrict__ Vh,
    const unsigned short* __restrict__ Vl,
    const unsigned short* __restrict__ Vth, const unsigned short* __restrict__ Vtl,
    float* __restrict__ Tpart, float* __restrict__ T0part,
    float* __restrict__ Lpart, float* __restrict__ WCpart,
    int SL, int nChunk)
{
  __shared__ unsigned short Wlds[4 * 32 * 68];

  const int tid = threadIdx.x;
  const int wave = tid >> 6, lane = tid & 63;
  const int lm = lane & 15;
  const int lg = lane >> 4;
  const int Wid = blockIdx.x * 4 + wave;
  const int slice = Wid % SL;
  const int sT = (Wid / SL) & 63;
  const int b = Wid / (SL * 64);
  const int sBase = b * 2048 + sT * 32;

  unsigned short* wbase = Wlds + wave * (32 * 68);

  short8 qf[2][2][2];
#pragma unroll
  for (int si = 0; si < 2; ++si)
#pragma unroll
    for (int ks = 0; ks < 2; ++ks) {
      int idx = (sBase + si * 16 + lm) * 64 + ks * 32 + lg * 8;
      qf[si][ks][0] = *(const short8*)(Qh + idx);
      qf[si][ks][1] = *(const short8*)(Ql + idx);
    }
  float q0r[2][4];
#pragma unroll
  for (int si = 0; si < 2; ++si)
#pragma unroll
    for (int r = 0; r < 4; ++r)
      q0r[si][r] = Q0g[sBase + si * 16 + lg * 4 + r];

  f32x4 accT[2][4];
  float Lp[2][4], WCp[2][4], T0p[2][4];
#pragma unroll
  for (int si = 0; si < 2; ++si)
#pragma unroll
    for (int r = 0; r < 4; ++r) {
      Lp[si][r] = 0.f; WCp[si][r] = 0.f; T0p[si][r] = 0.f;
    }
#pragma unroll
  for (int si = 0; si < 2; ++si)
#pragma unroll
    for (int dj = 0; dj < 4; ++dj) accT[si][dj] = f32x4{0.f, 0.f, 0.f, 0.f};

  const int mSliceBase = b * 4096 + slice * (nChunk * 64);
  for (int mc = 0; mc < nChunk; ++mc) {
    const int mCh = mSliceBase + (mc << 6);
    float k0r[4], v0r[4];
#pragma unroll
    for (int mj = 0; mj < 4; ++mj) {
      k0r[mj] = K0g[mCh + mj * 16 + lm];
      v0r[mj] = V0g[mCh + mj * 16 + lm];
    }

    // Phase A: sims = Qr.Kr, ipv = Qr.Vr via split-bf16 MFMA
    f32x4 sims[2][4], ipv[2][4];
#pragma unroll
    for (int si = 0; si < 2; ++si)
#pragma unroll
      for (int mj = 0; mj < 4; ++mj) {
        sims[si][mj] = f32x4{0.f, 0.f, 0.f, 0.f};
        ipv[si][mj]  = f32x4{0.f, 0.f, 0.f, 0.f};
      }
#pragma unroll
    for (int mj = 0; mj < 4; ++mj) {
#pragma unroll
      for (int ks = 0; ks < 2; ++ks) {
        int bidx = (mCh + mj * 16 + lm) * 64 + ks * 32 + lg * 8;
        short8 kh = *(const short8*)(Kh + bidx);
        short8 kl = *(const short8*)(Kl + bidx);
        short8 vh = *(const short8*)(Vh + bidx);
        short8 vl = *(const short8*)(Vl + bidx);
#pragma unroll
        for (int si = 0; si < 2; ++si) {
          sims[si][mj] = __builtin_amdgcn_mfma_f32_16x16x32_bf16(qf[si][ks][0], kh, sims[si][mj], 0, 0, 0);
          sims[si][mj] = __builtin_amdgcn_mfma_f32_16x16x32_bf16(qf[si][ks][0], kl, sims[si][mj], 0, 0, 0);
          sims[si][mj] = __builtin_amdgcn_mfma_f32_16x16x32_bf16(qf[si][ks][1], kh, sims[si][mj], 0, 0, 0);
          ipv[si][mj]  = __builtin_amdgcn_mfma_f32_16x16x32_bf16(qf[si][ks][0], vh, ipv[si][mj], 0, 0, 0);
          ipv[si][mj]  = __builtin_amdgcn_mfma_f32_16x16x32_bf16(qf[si][ks][0], vl, ipv[si][mj], 0, 0, 0);
          ipv[si][mj]  = __builtin_amdgcn_mfma_f32_16x16x32_bf16(qf[si][ks][1], vh, ipv[si][mj], 0, 0, 0);
        }
      }
    }

    // elementwise: w = e * acosh(-c) * rsq(c^2-1)
#pragma unroll
    for (int si = 0; si < 2; ++si)
#pragma unroll
      for (int mj = 0; mj < 4; ++mj)
#pragma unroll
        for (int r = 0; r < 4; ++r) {
          float c  = ipv[si][mj][r]  - q0r[si][r] * v0r[mj];
          float sm = sims[si][mj][r] - q0r[si][r] * k0r[mj];
          float x = -c;
          float s2 = fmaxf(fmaf(x, x, -1.0f), EPSF);
          float rs = __builtin_amdgcn_rsqf(s2);
          float dist = __logf(fmaf(s2, rs, x));
          float e = __expf(fmaf(-BETA, sm, -SHIFT));
          float w = e * dist * rs;
          unsigned short wu = bf16_rne(w);
          float wb = bf16_tof(wu);
          Lp[si][r]  += e;
          WCp[si][r] += wb * c;
          T0p[si][r] += wb * v0r[mj];
          wbase[(si * 16 + lg * 4 + r) * 68 + mj * 16 + lm] = wu;
        }

    // Phase B: T[s][d] += W[s][m] * V[m][d]
#pragma unroll
    for (int ks = 0; ks < 2; ++ks) {
      short8 wa[2];
#pragma unroll
      for (int si = 0; si < 2; ++si) {
        const unsigned short* p = wbase + (si * 16 + lm) * 68 + ks * 32 + lg * 8;
        short4v a0 = *(const short4v*)p;
        short4v a1 = *(const short4v*)(p + 4);
        wa[si] = __builtin_shufflevector(a0, a1, 0, 1, 2, 3, 4, 5, 6, 7);
      }
#pragma unroll
      for (int dj = 0; dj < 4; ++dj) {
        int vidx = (dj * 16 + lm) * 8192 + mCh + ks * 32 + lg * 8;
        short8 th = *(const short8*)(Vth + vidx);
        short8 tl = *(const short8*)(Vtl + vidx);
#pragma unroll
        for (int si = 0; si < 2; ++si) {
          accT[si][dj] = __builtin_amdgcn_mfma_f32_16x16x32_bf16(wa[si], th, accT[si][dj], 0, 0, 0);
          accT[si][dj] = __builtin_amdgcn_mfma_f32_16x16x32_bf16(wa[si], tl, accT[si][dj], 0, 0, 0);
        }
      }
    }
  }

#pragma unroll
  for (int si = 0; si < 2; ++si)
#pragma unroll
    for (int r = 0; r < 4; ++r)
#pragma unroll
      for (int off = 1; off < 16; off <<= 1) {
        Lp[si][r]  += __shfl_xor(Lp[si][r], off);
        WCp[si][r] += __shfl_xor(WCp[si][r], off);
        T0p[si][r] += __shfl_xor(T0p[si][r], off);
      }

  const int rowP = (slice << 12) + sBase;
#pragma unroll
  for (int si = 0; si < 2; ++si)
#pragma unroll
    for (int r = 0; r < 4; ++r) {
      int row = rowP + si * 16 + lg * 4 + r;
#pragma unroll
      for (int dj = 0; dj < 4; ++dj)
        Tpart[row * 64 + dj * 16 + lm] = accT[si][dj][r];
      if (lm == 0) {
        Lpart[row]  = Lp[si][r];
        WCpart[row] = WCp[si][r];
        T0part[row] = T0p[si][r];
      }
    }
}

// ---------------------------------------------------------------------------
// Combine: one wave per (b,s) row. f32 fast math; f64 only for the <t,t>
// reduction feeding the tangency identity mk = <t,t> + wc^2 (|wc|>=1 so
// un>=1; z0/zd cancellation <= ~50x so f32 leaves ~1e-5 abs error).
// ---------------------------------------------------------------------------
__global__ __launch_bounds__(256) void combine_kernel(
    const float* __restrict__ Q0, const unsigned short* __restrict__ Qh,
    const unsigned short* __restrict__ Ql,
    const float* __restrict__ Tpart, const float* __restrict__ T0part,
    const float* __restrict__ Lpart, const float* __restrict__ WCpart,
    float* __restrict__ out, int nSl)
{
  int wid = (blockIdx.x << 2) + (threadIdx.x >> 6);
  int lane = threadIdx.x & 63;

  float Tsum = 0.f, T0 = 0.f, L = 0.f, WC = 0.f;
  for (int sli = 0; sli < nSl; ++sli) {
    int rp = (sli << 12) + wid;
    Tsum += Tpart[rp * 64 + lane];
    T0 += T0part[rp];
    L  += Lpart[rp];
    WC += WCpart[rp];
  }
  int qi = wid * 64 + lane;
  float qd = bf16_tof(Qh[qi]) + bf16_tof(Ql[qi]);
  float q0 = Q0[wid];
  float invL = 1.0f / L;
  float td = Tsum * invL;
  float t0 = T0 * invL;
  float wc = WC * invL;

  double tt = (double)td * (double)td;
#pragma unroll
  for (int off = 1; off < 64; off <<= 1) tt += __shfl_xor(tt, off);
  tt -= (double)t0 * (double)t0;
  double mk = tt + (double)wc * (double)wc;

  float un = (float)sqrt(fmax(mk, 1e-12));
  float eu = __expf(un);
  float ru = 1.0f / eu;
  float ch = 0.5f * (eu + ru);
  float shu = 0.5f * (eu - ru) / un;

  float tmd = td + wc * qd;
  float tm0 = t0 + wc * q0;
  float zd = ch * qd + shu * tmd;
  float z0 = ch * q0 + shu * tm0;

  float p2 = zd * zd;
#pragma unroll
  for (int off = 1; off < 64; off <<= 1) p2 += __shfl_xor(p2, off);
  float yn = fmaxf(sqrtf(p2), EPSF);
  float zc = fmaxf(z0, 1.0f + EPSF);
  float dl = __logf(zc + sqrtf(fmaxf(zc * zc - 1.0f, 0.f)));
  out[qi] = dl * zd / yn;
}

// ---------------------------------------------------------------------------
extern "C" void kernel_launch(void* const* d_in, const int* in_sizes, int n_in,
                              void* d_out, int out_size, void* d_ws, size_t ws_size,
                              hipStream_t stream)
{
  const float* queries = (const float*)d_in[0];
  const float* keys    = (const float*)d_in[1];
  const float* values  = (const float*)d_in[2];
  const float* Wq      = (const float*)d_in[3];
  const float* bq      = (const float*)d_in[4];
  const float* Wk      = (const float*)d_in[5];
  const float* bk      = (const float*)d_in[6];
  const float* Wv      = (const float*)d_in[7];
  const float* bv      = (const float*)d_in[8];
  float* out = (float*)d_out;
  float* ws  = (float*)d_ws;

  const size_t base = 1855488;  // floats before Tpart
  auto need = [&](size_t sl) {
    return (base + sl * 4096 * 64 + 3 * sl * 4096) * 4;
  };
  int SL = 32;                          // 1024 WGs = 4 WGs/CU
  if (ws_size < need(32)) SL = (ws_size >= need(16)) ? 16 : 8;
  const int nChunk = 4096 / (SL * 64);

  float* Q0 = ws;                                   // 4096
  float* K0 = ws + 4096;                            // 8192
  float* V0 = ws + 12288;                           // 8192
  unsigned short* Qh  = (unsigned short*)(ws + 20480);
  unsigned short* Ql  = (unsigned short*)(ws + 151552);
  unsigned short* Kh  = (unsigned short*)(ws + 282624);
  unsigned short* Kl  = (unsigned short*)(ws + 544768);
  unsigned short* Vh  = (unsigned short*)(ws + 806912);
  unsigned short* Vl  = (unsigned short*)(ws + 1069056);
  unsigned short* Vth = (unsigned short*)(ws + 1331200);  // [64][8192]
  unsigned short* Vtl = (unsigned short*)(ws + 1593344);
  float* Tpart  = ws + base;
  float* T0part = Tpart + (size_t)SL * 4096 * 64;
  float* Lpart  = T0part + (size_t)SL * 4096;
  float* WCpart = Lpart + (size_t)SL * 4096;

  proj_kernel<<<320, 256, 0, stream>>>(queries, keys, values, Wq, bq, Wk, bk,
                                       Wv, bv, Q0, K0, V0, Qh, Ql, Kh, Kl,
                                       Vh, Vl);
  transpose_kernel<<<256, 256, 0, stream>>>(Vh, Vl, Vth, Vtl);
  attn_kernel<<<32 * SL, 256, 0, stream>>>(
      Q0, Qh, Ql, K0, Kh, Kl, V0, Vh, Vl, Vth, Vtl,
      Tpart, T0part, Lpart, WCpart, SL, nChunk);
  combine_kernel<<<1024, 256, 0, stream>>>(
      Q0, Qh, Ql, Tpart, T0part, Lpart, WCpart, out, SL);
}

// Round 8
// 163.813 us; speedup vs baseline: 1.1254x; 1.1254x over previous
//
#include <hip/hip_runtime.h>
#include <math.h>

#define BETA  0.125f    // 1/sqrt(64)
#define SHIFT 30.0f     // fixed softmax shift; logits bounded in [0.125, 68.5]
#define EPSF  1e-7f

typedef __attribute__((ext_vector_type(8))) short short8;
typedef __attribute__((ext_vector_type(4))) short short4v;
typedef __attribute__((ext_vector_type(4))) float f32x4;

__device__ __forceinline__ unsigned short bf16_rne(float x) {
  unsigned int u = __float_as_uint(x);
  return (unsigned short)((u + 0x7fffu + ((u >> 16) & 1u)) >> 16);
}
__device__ __forceinline__ float bf16_tof(unsigned short h) {
  return __uint_as_float(((unsigned int)h) << 16);
}
__device__ __forceinline__ void split2(float x, unsigned short& h, unsigned short& l) {
  unsigned int u = __float_as_uint(x);
  unsigned int hr = (u + 0x7fffu + ((u >> 16) & 1u)) & 0xffff0000u;  // RNE hi
  h = (unsigned short)(hr >> 16);
  l = bf16_rne(x - __uint_as_float(hr));
}

// ---------------------------------------------------------------------------
// Merged projection. Blocks 0..63: Q; 64..191: K; 192..319: V (double proj).
// Outputs: y0 = cosh (f32), spatial part split bf16 hi/lo (row-major);
// V blocks also emit the transposed copies via a DEDICATED LDS buffer
// (no aliasing of the GEMM tiles; two passes hi then lo).
// ---------------------------------------------------------------------------
__global__ __launch_bounds__(256) void proj_kernel(
    const float* __restrict__ Xq, const float* __restrict__ Xk,
    const float* __restrict__ Xv,
    const float* __restrict__ Wq, const float* __restrict__ bq,
    const float* __restrict__ Wk, const float* __restrict__ bk,
    const float* __restrict__ Wv, const float* __restrict__ bv,
    float* __restrict__ Q0, float* __restrict__ K0, float* __restrict__ V0,
    unsigned short* __restrict__ Qh, unsigned short* __restrict__ Ql,
    unsigned short* __restrict__ Kh, unsigned short* __restrict__ Kl,
    unsigned short* __restrict__ Vh, unsigned short* __restrict__ Vl,
    unsigned short* __restrict__ Vth, unsigned short* __restrict__ Vtl)
{
  __shared__ float Xs[64 * 64];
  __shared__ float Ws[64 * 64];
  __shared__ unsigned int Tr[64 * 65];   // dedicated transpose buffer (V only)

  const int bid = blockIdx.x;
  const float *X, *W, *bias;
  float* y0;
  unsigned short *yh, *yl;
  bool dbl;
  int rowBase;
  if (bid < 64)       { X = Xq; W = Wq; bias = bq; y0 = Q0; yh = Qh; yl = Ql; rowBase = bid << 6;         dbl = false; }
  else if (bid < 192) { X = Xk; W = Wk; bias = bk; y0 = K0; yh = Kh; yl = Kl; rowBase = (bid - 64) << 6;  dbl = false; }
  else                { X = Xv; W = Wk; bias = bk; y0 = V0; yh = Vh; yl = Vl; rowBase = (bid - 192) << 6; dbl = true;  }

  const int tid = threadIdx.x;
  const int ty = tid >> 4, tx = tid & 15;
  const int ty4 = ty << 2, tx4 = tx << 2;

  float acc[4][4];
#pragma unroll
  for (int j = 0; j < 4; ++j) {
    float bj = bias[tx4 + j];
#pragma unroll
    for (int i = 0; i < 4; ++i) acc[i][j] = bj;
  }

  for (int kc = 0; kc < 4; ++kc) {
#pragma unroll
    for (int q = 0; q < 4; ++q) {
      int f = tid + (q << 8);
      int r = f >> 4, g = f & 15;
      int sw = (r << 6) + ((g ^ (r >> 2)) << 2);
      *(float4*)&Xs[sw] = *(const float4*)&X[(rowBase + r) * 256 + (kc << 6) + (g << 2)];
      *(float4*)&Ws[sw] = *(const float4*)&W[r * 256 + (kc << 6) + (g << 2)];
    }
    __syncthreads();
#pragma unroll 4
    for (int kk = 0; kk < 64; kk += 4) {
      const int gk = kk >> 2;
      float4 xa[4], wb[4];
#pragma unroll
      for (int i = 0; i < 4; ++i)
        xa[i] = *(const float4*)&Xs[((ty4 + i) << 6) + ((gk ^ ty) << 2)];
#pragma unroll
      for (int j = 0; j < 4; ++j)
        wb[j] = *(const float4*)&Ws[((tx4 + j) << 6) + ((gk ^ tx) << 2)];
#pragma unroll
      for (int i = 0; i < 4; ++i)
#pragma unroll
        for (int j = 0; j < 4; ++j)
          acc[i][j] += xa[i].x * wb[j].x + xa[i].y * wb[j].y +
                       xa[i].z * wb[j].z + xa[i].w * wb[j].w;
    }
    __syncthreads();
  }

  if (dbl) {
#pragma unroll
    for (int i = 0; i < 4; ++i) {
      float4 v = make_float4(acc[i][0], acc[i][1], acc[i][2], acc[i][3]);
      *(float4*)&Xs[((ty4 + i) << 6) + ((tx ^ ty) << 2)] = v;
    }
#pragma unroll
    for (int q = 0; q < 4; ++q) {
      int f = tid + (q << 8);
      int r = f >> 4, g = f & 15;
      int sw = (r << 6) + ((g ^ (r >> 2)) << 2);
      *(float4*)&Ws[sw] = *(const float4*)&Wv[(r << 6) + (g << 2)];
    }
#pragma unroll
    for (int j = 0; j < 4; ++j) {
      float bj = bv[tx4 + j];
#pragma unroll
      for (int i = 0; i < 4; ++i) acc[i][j] = bj;
    }
    __syncthreads();
#pragma unroll 4
    for (int kk = 0; kk < 64; kk += 4) {
      const int gk = kk >> 2;
      float4 xa[4], wb[4];
#pragma unroll
      for (int i = 0; i < 4; ++i)
        xa[i] = *(const float4*)&Xs[((ty4 + i) << 6) + ((gk ^ ty) << 2)];
#pragma unroll
      for (int j = 0; j < 4; ++j)
        wb[j] = *(const float4*)&Ws[((tx4 + j) << 6) + ((gk ^ tx) << 2)];
#pragma unroll
      for (int i = 0; i < 4; ++i)
#pragma unroll
        for (int j = 0; j < 4; ++j)
          acc[i][j] += xa[i].x * wb[j].x + xa[i].y * wb[j].y +
                       xa[i].z * wb[j].z + xa[i].w * wb[j].w;
    }
  }

  // expmap0 epilogue in registers + shuffles
  float n2p[4];
#pragma unroll
  for (int i = 0; i < 4; ++i)
    n2p[i] = acc[i][0] * acc[i][0] + acc[i][1] * acc[i][1] +
             acc[i][2] * acc[i][2] + acc[i][3] * acc[i][3];
#pragma unroll
  for (int i = 0; i < 4; ++i) {
    n2p[i] += __shfl_xor(n2p[i], 1);
    n2p[i] += __shfl_xor(n2p[i], 2);
    n2p[i] += __shfl_xor(n2p[i], 4);
    n2p[i] += __shfl_xor(n2p[i], 8);
  }
  unsigned short hv[4][4], lv[4][4];
#pragma unroll
  for (int i = 0; i < 4; ++i) {
    float n = sqrtf(n2p[i]);
    float factor = fminf(3.5f / (n + EPSF), 1.0f);
    float xn = fmaxf(n * factor, EPSF);
    float et = __expf(xn);
    float rt = __builtin_amdgcn_rcpf(et);
    float ch = 0.5f * (et + rt);
    float sh = 0.5f * (et - rt);
    float scale = sh * factor * __builtin_amdgcn_rcpf(xn);
    int row = rowBase + ty4 + i;
    if (tx == 0) y0[row] = ch;
#pragma unroll
    for (int j = 0; j < 4; ++j) split2(acc[i][j] * scale, hv[i][j], lv[i][j]);
    unsigned int* ph = (unsigned int*)(yh + row * 64 + tx4);
    ph[0] = (unsigned int)hv[i][0] | ((unsigned int)hv[i][1] << 16);
    ph[1] = (unsigned int)hv[i][2] | ((unsigned int)hv[i][3] << 16);
    unsigned int* pl = (unsigned int*)(yl + row * 64 + tx4);
    pl[0] = (unsigned int)lv[i][0] | ((unsigned int)lv[i][1] << 16);
    pl[1] = (unsigned int)lv[i][2] | ((unsigned int)lv[i][3] << 16);
  }

  if (dbl) {
    // transposed copies via dedicated LDS buffer; two passes (hi, lo)
#pragma unroll
    for (int i = 0; i < 4; ++i)
#pragma unroll
      for (int j = 0; j < 4; ++j)
        Tr[(ty4 + i) * 65 + tx4 + j] = (unsigned int)hv[i][j];
    __syncthreads();
#pragma unroll
    for (int q = 0; q < 2; ++q) {
      int f = tid + (q << 8);
      int d = f >> 3;                // 0..63
      int seg = (f & 7) << 3;        // 0,8,..,56
      unsigned int o[4];
#pragma unroll
      for (int k = 0; k < 4; ++k)
        o[k] = Tr[(seg + 2 * k) * 65 + d] | (Tr[(seg + 2 * k + 1) * 65 + d] << 16);
      *(uint4*)&Vth[d * 8192 + rowBase + seg] = make_uint4(o[0], o[1], o[2], o[3]);
    }
    __syncthreads();
#pragma unroll
    for (int i = 0; i < 4; ++i)
#pragma unroll
      for (int j = 0; j < 4; ++j)
        Tr[(ty4 + i) * 65 + tx4 + j] = (unsigned int)lv[i][j];
    __syncthreads();
#pragma unroll
    for (int q = 0; q < 2; ++q) {
      int f = tid + (q << 8);
      int d = f >> 3;
      int seg = (f & 7) << 3;
      unsigned int o[4];
#pragma unroll
      for (int k = 0; k < 4; ++k)
        o[k] = Tr[(seg + 2 * k) * 65 + d] | (Tr[(seg + 2 * k + 1) * 65 + d] << 16);
      *(uint4*)&Vtl[d * 8192 + rowBase + seg] = make_uint4(o[0], o[1], o[2], o[3]);
    }
  }
}

// ---------------------------------------------------------------------------
// MFMA attention core (round-5 body, tripwire-proven at SL=16). One wave =
// 32 s-rows x one m-slice; per-wave-private LDS, zero __syncthreads.
// ---------------------------------------------------------------------------
__global__ void __attribute__((amdgpu_waves_per_eu(2, 2)))
__launch_bounds__(256) attn_kernel(
    const float* __restrict__ Q0g, const unsigned short* __restrict__ Qh,
    const unsigned short* __restrict__ Ql,
    const float* __restrict__ K0g, const unsigned short* __restrict__ Kh,
    const unsigned short* __restrict__ Kl,
    const float* __restrict__ V0g, const unsigned short* __restrict__ Vh,
    const unsigned short* __restrict__ Vl,
    const unsigned short* __restrict__ Vth, const unsigned short* __restrict__ Vtl,
    float* __restrict__ Tpart, float* __restrict__ T0part,
    float* __restrict__ Lpart, float* __restrict__ WCpart,
    int SL, int nChunk)
{
  __shared__ unsigned short Wlds[4 * 32 * 68];

  const int tid = threadIdx.x;
  const int wave = tid >> 6, lane = tid & 63;
  const int lm = lane & 15;
  const int lg = lane >> 4;
  const int Wid = blockIdx.x * 4 + wave;
  const int slice = Wid % SL;
  const int sT = (Wid / SL) & 63;
  const int b = Wid / (SL * 64);
  const int sBase = b * 2048 + sT * 32;

  unsigned short* wbase = Wlds + wave * (32 * 68);

  short8 qf[2][2][2];
#pragma unroll
  for (int si = 0; si < 2; ++si)
#pragma unroll
    for (int ks = 0; ks < 2; ++ks) {
      int idx = (sBase + si * 16 + lm) * 64 + ks * 32 + lg * 8;
      qf[si][ks][0] = *(const short8*)(Qh + idx);
      qf[si][ks][1] = *(const short8*)(Ql + idx);
    }
  float q0r[2][4];
#pragma unroll
  for (int si = 0; si < 2; ++si)
#pragma unroll
    for (int r = 0; r < 4; ++r)
      q0r[si][r] = Q0g[sBase + si * 16 + lg * 4 + r];

  f32x4 accT[2][4];
  float Lp[2][4], WCp[2][4], T0p[2][4];
#pragma unroll
  for (int si = 0; si < 2; ++si)
#pragma unroll
    for (int r = 0; r < 4; ++r) {
      Lp[si][r] = 0.f; WCp[si][r] = 0.f; T0p[si][r] = 0.f;
    }
#pragma unroll
  for (int si = 0; si < 2; ++si)
#pragma unroll
    for (int dj = 0; dj < 4; ++dj) accT[si][dj] = f32x4{0.f, 0.f, 0.f, 0.f};

  const int mSliceBase = b * 4096 + slice * (nChunk * 64);
  for (int mc = 0; mc < nChunk; ++mc) {
    const int mCh = mSliceBase + (mc << 6);
    float k0r[4], v0r[4];
#pragma unroll
    for (int mj = 0; mj < 4; ++mj) {
      k0r[mj] = K0g[mCh + mj * 16 + lm];
      v0r[mj] = V0g[mCh + mj * 16 + lm];
    }

    // Phase A: sims = Qr.Kr, ipv = Qr.Vr via split-bf16 MFMA
    f32x4 sims[2][4], ipv[2][4];
#pragma unroll
    for (int si = 0; si < 2; ++si)
#pragma unroll
      for (int mj = 0; mj < 4; ++mj) {
        sims[si][mj] = f32x4{0.f, 0.f, 0.f, 0.f};
        ipv[si][mj]  = f32x4{0.f, 0.f, 0.f, 0.f};
      }
#pragma unroll
    for (int mj = 0; mj < 4; ++mj) {
#pragma unroll
      for (int ks = 0; ks < 2; ++ks) {
        int bidx = (mCh + mj * 16 + lm) * 64 + ks * 32 + lg * 8;
        short8 kh = *(const short8*)(Kh + bidx);
        short8 kl = *(const short8*)(Kl + bidx);
        short8 vh = *(const short8*)(Vh + bidx);
        short8 vl = *(const short8*)(Vl + bidx);
#pragma unroll
        for (int si = 0; si < 2; ++si) {
          sims[si][mj] = __builtin_amdgcn_mfma_f32_16x16x32_bf16(qf[si][ks][0], kh, sims[si][mj], 0, 0, 0);
          sims[si][mj] = __builtin_amdgcn_mfma_f32_16x16x32_bf16(qf[si][ks][0], kl, sims[si][mj], 0, 0, 0);
          sims[si][mj] = __builtin_amdgcn_mfma_f32_16x16x32_bf16(qf[si][ks][1], kh, sims[si][mj], 0, 0, 0);
          ipv[si][mj]  = __builtin_amdgcn_mfma_f32_16x16x32_bf16(qf[si][ks][0], vh, ipv[si][mj], 0, 0, 0);
          ipv[si][mj]  = __builtin_amdgcn_mfma_f32_16x16x32_bf16(qf[si][ks][0], vl, ipv[si][mj], 0, 0, 0);
          ipv[si][mj]  = __builtin_amdgcn_mfma_f32_16x16x32_bf16(qf[si][ks][1], vh, ipv[si][mj], 0, 0, 0);
        }
      }
    }

    // elementwise: w = e * acosh(-c) * rsq(c^2-1)
#pragma unroll
    for (int si = 0; si < 2; ++si)
#pragma unroll
      for (int mj = 0; mj < 4; ++mj)
#pragma unroll
        for (int r = 0; r < 4; ++r) {
          float c  = ipv[si][mj][r]  - q0r[si][r] * v0r[mj];
          float sm = sims[si][mj][r] - q0r[si][r] * k0r[mj];
          float x = -c;
          float s2 = fmaxf(fmaf(x, x, -1.0f), EPSF);
          float rs = __builtin_amdgcn_rsqf(s2);
          float dist = __logf(fmaf(s2, rs, x));
          float e = __expf(fmaf(-BETA, sm, -SHIFT));
          float w = e * dist * rs;
          unsigned short wu = bf16_rne(w);
          float wb = bf16_tof(wu);
          Lp[si][r]  += e;
          WCp[si][r] += wb * c;
          T0p[si][r] += wb * v0r[mj];
          wbase[(si * 16 + lg * 4 + r) * 68 + mj * 16 + lm] = wu;
        }

    // Phase B: T[s][d] += W[s][m] * V[m][d]
#pragma unroll
    for (int ks = 0; ks < 2; ++ks) {
      short8 wa[2];
#pragma unroll
      for (int si = 0; si < 2; ++si) {
        const unsigned short* p = wbase + (si * 16 + lm) * 68 + ks * 32 + lg * 8;
        short4v a0 = *(const short4v*)p;
        short4v a1 = *(const short4v*)(p + 4);
        wa[si] = __builtin_shufflevector(a0, a1, 0, 1, 2, 3, 4, 5, 6, 7);
      }
#pragma unroll
      for (int dj = 0; dj < 4; ++dj) {
        int vidx = (dj * 16 + lm) * 8192 + mCh + ks * 32 + lg * 8;
        short8 th = *(const short8*)(Vth + vidx);
        short8 tl = *(const short8*)(Vtl + vidx);
#pragma unroll
        for (int si = 0; si < 2; ++si) {
          accT[si][dj] = __builtin_amdgcn_mfma_f32_16x16x32_bf16(wa[si], th, accT[si][dj], 0, 0, 0);
          accT[si][dj] = __builtin_amdgcn_mfma_f32_16x16x32_bf16(wa[si], tl, accT[si][dj], 0, 0, 0);
        }
      }
    }
  }

#pragma unroll
  for (int si = 0; si < 2; ++si)
#pragma unroll
    for (int r = 0; r < 4; ++r)
#pragma unroll
      for (int off = 1; off < 16; off <<= 1) {
        Lp[si][r]  += __shfl_xor(Lp[si][r], off);
        WCp[si][r] += __shfl_xor(WCp[si][r], off);
        T0p[si][r] += __shfl_xor(T0p[si][r], off);
      }

  const int rowP = (slice << 12) + sBase;
#pragma unroll
  for (int si = 0; si < 2; ++si)
#pragma unroll
    for (int r = 0; r < 4; ++r) {
      int row = rowP + si * 16 + lg * 4 + r;
#pragma unroll
      for (int dj = 0; dj < 4; ++dj)
        Tpart[row * 64 + dj * 16 + lm] = accT[si][dj][r];
      if (lm == 0) {
        Lpart[row]  = Lp[si][r];
        WCpart[row] = WCp[si][r];
        T0part[row] = T0p[si][r];
      }
    }
}

// ---------------------------------------------------------------------------
// Combine: one wave per (b,s) row. f32 fast math; f64 only for the <t,t>
// reduction feeding the tangency identity mk = <t,t> + wc^2.
// ---------------------------------------------------------------------------
__global__ __launch_bounds__(256) void combine_kernel(
    const float* __restrict__ Q0, const unsigned short* __restrict__ Qh,
    const unsigned short* __restrict__ Ql,
    const float* __restrict__ Tpart, const float* __restrict__ T0part,
    const float* __restrict__ Lpart, const float* __restrict__ WCpart,
    float* __restrict__ out, int nSl)
{
  int wid = (blockIdx.x << 2) + (threadIdx.x >> 6);
  int lane = threadIdx.x & 63;

  float Tsum = 0.f, T0 = 0.f, L = 0.f, WC = 0.f;
#pragma unroll 4
  for (int sli = 0; sli < nSl; ++sli) {
    int rp = (sli << 12) + wid;
    Tsum += Tpart[rp * 64 + lane];
    T0 += T0part[rp];
    L  += Lpart[rp];
    WC += WCpart[rp];
  }
  int qi = wid * 64 + lane;
  float qd = bf16_tof(Qh[qi]) + bf16_tof(Ql[qi]);
  float q0 = Q0[wid];
  float invL = 1.0f / L;
  float td = Tsum * invL;
  float t0 = T0 * invL;
  float wc = WC * invL;

  double tt = (double)td * (double)td;
#pragma unroll
  for (int off = 1; off < 64; off <<= 1) tt += __shfl_xor(tt, off);
  tt -= (double)t0 * (double)t0;
  double mk = tt + (double)wc * (double)wc;

  float un = (float)sqrt(fmax(mk, 1e-12));
  float eu = __expf(un);
  float ru = 1.0f / eu;
  float ch = 0.5f * (eu + ru);
  float shu = 0.5f * (eu - ru) / un;

  float tmd = td + wc * qd;
  float tm0 = t0 + wc * q0;
  float zd = ch * qd + shu * tmd;
  float z0 = ch * q0 + shu * tm0;

  float p2 = zd * zd;
#pragma unroll
  for (int off = 1; off < 64; off <<= 1) p2 += __shfl_xor(p2, off);
  float yn = fmaxf(sqrtf(p2), EPSF);
  float zc = fmaxf(z0, 1.0f + EPSF);
  float dl = __logf(zc + sqrtf(fmaxf(zc * zc - 1.0f, 0.f)));
  out[qi] = dl * zd / yn;
}

// ---------------------------------------------------------------------------
extern "C" void kernel_launch(void* const* d_in, const int* in_sizes, int n_in,
                              void* d_out, int out_size, void* d_ws, size_t ws_size,
                              hipStream_t stream)
{
  const float* queries = (const float*)d_in[0];
  const float* keys    = (const float*)d_in[1];
  const float* values  = (const float*)d_in[2];
  const float* Wq      = (const float*)d_in[3];
  const float* bq      = (const float*)d_in[4];
  const float* Wk      = (const float*)d_in[5];
  const float* bk      = (const float*)d_in[6];
  const float* Wv      = (const float*)d_in[7];
  const float* bv      = (const float*)d_in[8];
  float* out = (float*)d_out;
  float* ws  = (float*)d_ws;

  const size_t base = 1855488;  // floats before Tpart
  auto need = [&](size_t sl) {
    return (base + sl * 4096 * 64 + 3 * sl * 4096) * 4;
  };
  int SL = 16;                          // proven-fastest slicing (r5: 60.6 us)
  if (ws_size < need(16)) SL = 8;
  const int nChunk = 4096 / (SL * 64);

  float* Q0 = ws;                                   // 4096
  float* K0 = ws + 4096;                            // 8192
  float* V0 = ws + 12288;                           // 8192
  unsigned short* Qh  = (unsigned short*)(ws + 20480);
  unsigned short* Ql  = (unsigned short*)(ws + 151552);
  unsigned short* Kh  = (unsigned short*)(ws + 282624);
  unsigned short* Kl  = (unsigned short*)(ws + 544768);
  unsigned short* Vh  = (unsigned short*)(ws + 806912);
  unsigned short* Vl  = (unsigned short*)(ws + 1069056);
  unsigned short* Vth = (unsigned short*)(ws + 1331200);  // [64][8192]
  unsigned short* Vtl = (unsigned short*)(ws + 1593344);
  float* Tpart  = ws + base;
  float* T0part = Tpart + (size_t)SL * 4096 * 64;
  float* Lpart  = T0part + (size_t)SL * 4096;
  float* WCpart = Lpart + (size_t)SL * 4096;

  proj_kernel<<<320, 256, 0, stream>>>(queries, keys, values, Wq, bq, Wk, bk,
                                       Wv, bv, Q0, K0, V0, Qh, Ql, Kh, Kl,
                                       Vh, Vl, Vth, Vtl);
  attn_kernel<<<32 * SL, 256, 0, stream>>>(
      Q0, Qh, Ql, K0, Kh, Kl, V0, Vh, Vl, Vth, Vtl,
      Tpart, T0part, Lpart, WCpart, SL, nChunk);
  combine_kernel<<<1024, 256, 0, stream>>>(
      Q0, Qh, Ql, Tpart, T0part, Lpart, WCpart, out, SL);
}